// Round 2
// baseline (7391.454 us; speedup 1.0000x reference)
//
#include <hip/hip_runtime.h>
#include <math.h>

#define FHh 100
#define FWw 160
#define CIN 512
#define COUT 512
#define NPIX 16000
#define NANCH 144000
#define PRE_NMS 6000
#define POST_NMS 300
#define EQCAP 8192

// monotonic fp32 -> u32 key
__device__ __forceinline__ unsigned fkey(float x){
  unsigned b = __float_as_uint(x);
  return (b & 0x80000000u) ? ~b : (b | 0x80000000u);
}
// monotonic fp64 -> u64 key
__device__ __forceinline__ unsigned long long dkey(double x){
  unsigned long long u = (unsigned long long)__double_as_longlong(x);
  return (u & 0x8000000000000000ull) ? ~u : (u | 0x8000000000000000ull);
}
__device__ __forceinline__ unsigned long long shfl_down_u64(unsigned long long x, int off){
  unsigned lo = (unsigned)x, hi = (unsigned)(x >> 32);
  lo = __shfl_down(lo, off, 64);
  hi = __shfl_down(hi, off, 64);
  return ((unsigned long long)hi << 32) | lo;
}

// ---------------- fused 3x3 conv (f64 acc) + bias/relu + 1x1 heads ----------------
__global__ __launch_bounds__(256) void conv_head(
    const float* __restrict__ fm, const float* __restrict__ W1, const float* __restrict__ b1,
    const float* __restrict__ Wc, const float* __restrict__ bc,
    const float* __restrict__ Wr, const float* __restrict__ br,
    float* __restrict__ out, double* __restrict__ scored, double* __restrict__ regd)
{
  __shared__ double yl[16][512];                 // 64 KB: y tile for the 1x1 heads
  const int bid = blockIdx.x;                    // 1000 blocks
  const int py  = bid / 10;
  const int px0 = (bid - py*10) * 16;
  const int t   = threadIdx.x;                   // couts t and t+256
  double acc0[16], acc1[16];
  #pragma unroll
  for (int p = 0; p < 16; ++p){ acc0[p] = 0.0; acc1[p] = 0.0; }

  for (int dy = -1; dy <= 1; ++dy){
    const int yy = py + dy;
    if (yy < 0 || yy >= FHh) continue;
    const float* frow = fm + (size_t)yy * FWw * CIN;
    for (int dx = -1; dx <= 1; ++dx){
      const float* wb = W1 + (size_t)((dy+1)*3 + (dx+1)) * CIN * COUT;
      const int xlo = px0 + dx;
      if (xlo >= 0 && xlo + 15 < FWw){
        const float* f0 = frow + (size_t)xlo * CIN;
        for (int ci = 0; ci < CIN; ci += 4){
          const double w00=(double)wb[(ci+0)*COUT+t],     w01=(double)wb[(ci+1)*COUT+t];
          const double w02=(double)wb[(ci+2)*COUT+t],     w03=(double)wb[(ci+3)*COUT+t];
          const double w10=(double)wb[(ci+0)*COUT+t+256], w11=(double)wb[(ci+1)*COUT+t+256];
          const double w12=(double)wb[(ci+2)*COUT+t+256], w13=(double)wb[(ci+3)*COUT+t+256];
          #pragma unroll
          for (int p = 0; p < 16; ++p){
            const float4 vf = *(const float4*)&f0[(size_t)p*CIN + ci];
            const double v0=(double)vf.x, v1=(double)vf.y, v2=(double)vf.z, v3=(double)vf.w;
            acc0[p] = fma(v0,w00,acc0[p]); acc0[p] = fma(v1,w01,acc0[p]);
            acc0[p] = fma(v2,w02,acc0[p]); acc0[p] = fma(v3,w03,acc0[p]);
            acc1[p] = fma(v0,w10,acc1[p]); acc1[p] = fma(v1,w11,acc1[p]);
            acc1[p] = fma(v2,w12,acc1[p]); acc1[p] = fma(v3,w13,acc1[p]);
          }
        }
      } else {
        for (int ci = 0; ci < CIN; ++ci){
          const double w0d=(double)wb[ci*COUT+t], w1d=(double)wb[ci*COUT+t+256];
          #pragma unroll
          for (int p = 0; p < 16; ++p){
            const int xx = xlo + p;
            const float v = (xx >= 0 && xx < FWw) ? frow[(size_t)xx*CIN + ci] : 0.f;
            const double vd = (double)v;
            acc0[p] = fma(vd, w0d, acc0[p]);
            acc1[p] = fma(vd, w1d, acc1[p]);
          }
        }
      }
    }
  }
  const double bb0 = (double)b1[t], bb1 = (double)b1[t + 256];
  #pragma unroll
  for (int p = 0; p < 16; ++p){
    yl[p][t]       = fmax(acc0[p] + bb0, 0.0);
    yl[p][t + 256] = fmax(acc1[p] + bb1, 0.0);
  }
  __syncthreads();

  // 1x1 heads: 16 px x 45 outs = 720 dot products of length 512 (f64)
  for (int j = t; j < 720; j += 256){
    const int p = j / 45, n = j - p*45;
    const double* yr = yl[p];
    double s = 0.0;
    if (n < 9){
      for (int ci = 0; ci < CIN; ++ci) s = fma(yr[ci], (double)Wc[ci*9 + n], s);
      s += (double)bc[n];
      const double sig = 1.0 / (1.0 + exp(-s));
      const int gi = (py*FWw + px0 + p)*9 + n;
      out[gi] = (float)sig;
      scored[gi] = sig;
    } else {
      const int m = n - 9;
      for (int ci = 0; ci < CIN; ++ci) s = fma(yr[ci], (double)Wr[ci*36 + m], s);
      s += (double)br[m];
      const int gi = (py*FWw + px0 + p)*36 + m;
      out[144000 + gi] = (float)s;
      regd[gi] = s;
    }
  }
}

// ---------------- decode + clip + min-size (all f64) ----------------
__global__ __launch_bounds__(256) void decode_kernel(
    const float* __restrict__ amap, const double* __restrict__ scored,
    const double* __restrict__ regd, double* __restrict__ boxesd,
    unsigned* __restrict__ key32, unsigned long long* __restrict__ nmskey)
{
  const int i = blockIdx.x*256 + threadIdx.x;
  if (i >= NANCH) return;
  const double a0=(double)amap[4*i+0], a1=(double)amap[4*i+1];
  const double a2=(double)amap[4*i+2], a3=(double)amap[4*i+3];
  const double d0=regd[4*i+0], d1=regd[4*i+1], d2=regd[4*i+2], d3=regd[4*i+3];
  const double ah = a2 - a0, aw = a3 - a1;
  const double cy = a0 + 0.5*ah + d0*ah;
  const double cx = a1 + 0.5*aw + d1*aw;
  const double h = ah * exp(d2), w = aw * exp(d3);
  double y1 = cy - 0.5*h, x1 = cx - 0.5*w, y2 = cy + 0.5*h, x2 = cx + 0.5*w;
  y1 = fmax(y1, 0.0); x1 = fmax(x1, 0.0);
  y2 = fmin(y2, 1600.0); x2 = fmin(x2, 2560.0);
  boxesd[4*i+0]=y1; boxesd[4*i+1]=x1; boxesd[4*i+2]=y2; boxesd[4*i+3]=x2;
  const double obj = scored[i];
  const bool ok = (y2 - y1 >= 16.0) && (x2 - x1 >= 16.0);
  key32[i] = fkey((float)obj);                       // raw score, f32-rounded (radix bins)
  nmskey[i] = ok ? dkey(obj) : dkey(-1e9);           // masked f64 score key for NMS
}

// ---------------- top-6000 radix select on f32-rounded keys ----------------
__global__ __launch_bounds__(256) void hist_hi(const unsigned* __restrict__ key, unsigned* __restrict__ hist){
  const int i = blockIdx.x*256 + threadIdx.x;
  if (i < NANCH) atomicAdd(&hist[key[i] >> 16], 1u);
}

__global__ __launch_bounds__(1024) void scan_hi(const unsigned* __restrict__ hist, int* __restrict__ meta){
  __shared__ unsigned part[1024];
  const int t = threadIdx.x;
  unsigned s = 0;
  for (int j = 0; j < 64; ++j) s += hist[65535 - (t*64 + j)];
  part[t] = s;
  __syncthreads();
  for (int off = 1; off < 1024; off <<= 1){
    unsigned v = (t >= off) ? part[t - off] : 0u;
    __syncthreads();
    part[t] += v;
    __syncthreads();
  }
  const unsigned incl = part[t], excl = incl - s;
  if (excl < PRE_NMS && incl >= PRE_NMS){
    unsigned cum = excl;
    for (int j = 0; j < 64; ++j){
      const int bin = 65535 - (t*64 + j);
      const unsigned c = hist[bin];
      if (cum + c >= PRE_NMS){ meta[0] = bin; meta[1] = (int)cum; break; }
      cum += c;
    }
  }
}

__global__ __launch_bounds__(256) void hist_lo(const unsigned* __restrict__ key,
                                               const int* __restrict__ meta, unsigned* __restrict__ hist){
  const int i = blockIdx.x*256 + threadIdx.x;
  if (i < NANCH){
    const unsigned k = key[i];
    if ((int)(k >> 16) == meta[0]) atomicAdd(&hist[k & 0xFFFFu], 1u);
  }
}

__global__ __launch_bounds__(1024) void scan_lo(const unsigned* __restrict__ hist, int* __restrict__ meta){
  __shared__ unsigned part[1024];
  const int t = threadIdx.x;
  const unsigned G0 = (unsigned)meta[1];
  unsigned s = 0;
  for (int j = 0; j < 64; ++j) s += hist[65535 - (t*64 + j)];
  part[t] = s;
  __syncthreads();
  for (int off = 1; off < 1024; off <<= 1){
    unsigned v = (t >= off) ? part[t - off] : 0u;
    __syncthreads();
    part[t] += v;
    __syncthreads();
  }
  const unsigned incl = G0 + part[t], excl = incl - s;
  if (excl < PRE_NMS && incl >= PRE_NMS){
    unsigned cum = excl;
    for (int j = 0; j < 64; ++j){
      const int bin = 65535 - (t*64 + j);
      const unsigned c = hist[bin];
      if (cum + c >= PRE_NMS){
        meta[2] = (int)(((unsigned)meta[0] << 16) | (unsigned)bin);  // threshold f32 key T
        meta[3] = (int)cum;                                          // G2 = count(key > T)
        meta[4] = PRE_NMS - (int)cum;                                // R ties to take
        break;
      }
      cum += c;
    }
  }
}

__global__ __launch_bounds__(256) void compact_k(
    const unsigned* __restrict__ key, const unsigned long long* __restrict__ nmskey,
    const double* __restrict__ boxesd, const int* __restrict__ meta,
    int* __restrict__ cnt, double* __restrict__ selboxd,
    unsigned long long* __restrict__ selkey, int* __restrict__ eqidx)
{
  const int i = blockIdx.x*256 + threadIdx.x;
  if (i >= NANCH) return;
  const unsigned k = key[i];
  const unsigned T = (unsigned)meta[2];
  if (k > T){
    const int s = atomicAdd(&cnt[0], 1);
    selboxd[4*s+0]=boxesd[4*i+0]; selboxd[4*s+1]=boxesd[4*i+1];
    selboxd[4*s+2]=boxesd[4*i+2]; selboxd[4*s+3]=boxesd[4*i+3];
    selkey[s] = nmskey[i];
  } else if (k == T){
    const int e = atomicAdd(&cnt[1], 1);
    if (e < EQCAP) eqidx[e] = i;
  }
}

// threshold ties ranked by (f64 score desc, anchor idx asc) — exact lax.top_k emulation
__global__ __launch_bounds__(256) void rankeq(
    const double* __restrict__ scored, const double* __restrict__ boxesd,
    const unsigned long long* __restrict__ nmskey,
    const int* __restrict__ meta, const int* __restrict__ cnt,
    const int* __restrict__ eqidx, double* __restrict__ selboxd,
    unsigned long long* __restrict__ selkey)
{
  __shared__ int eq[EQCAP];
  const int t = threadIdx.x;
  int E = cnt[1]; if (E > EQCAP) E = EQCAP;
  const int R = meta[4], G2 = meta[3];
  for (int j = t; j < E; j += 256) eq[j] = eqidx[j];
  __syncthreads();
  for (int j = t; j < E; j += 256){
    const int my = eq[j];
    const double smy = scored[my];
    int rank = 0;
    for (int k2 = 0; k2 < E; ++k2){
      const int ok = eq[k2];
      const double sk = scored[ok];
      rank += ((sk > smy) || (sk == smy && ok < my)) ? 1 : 0;
    }
    if (rank < R){
      const int s = G2 + rank;
      selboxd[4*s+0]=boxesd[4*my+0]; selboxd[4*s+1]=boxesd[4*my+1];
      selboxd[4*s+2]=boxesd[4*my+2]; selboxd[4*s+3]=boxesd[4*my+3];
      selkey[s] = nmskey[my];
    }
  }
}

// ---------------- greedy NMS, 300 iters, f64 IOU, boxes register-cached ----------------
__global__ __launch_bounds__(1024) void nms_k(
    const double* __restrict__ selboxd, const unsigned long long* __restrict__ selkey,
    float* __restrict__ outp)
{
  __shared__ unsigned long long skey[PRE_NMS];   // 48 KB
  __shared__ unsigned long long wk[16];
  __shared__ int wj[16];
  __shared__ double bbox[4];
  __shared__ unsigned long long bk_s;
  __shared__ int bj_s;
  const int t = threadIdx.x;
  double cb[6][4];
  {
    int jj = 0;
    for (int j = t; j < PRE_NMS; j += 1024){
      skey[j] = selkey[j];
      cb[jj][0]=selboxd[4*j+0]; cb[jj][1]=selboxd[4*j+1];
      cb[jj][2]=selboxd[4*j+2]; cb[jj][3]=selboxd[4*j+3];
      ++jj;
    }
  }
  __syncthreads();
  const unsigned long long KEYNEG = dkey(-1e9);

  for (int r = 0; r < POST_NMS; ++r){
    unsigned long long mk = 0ull; int mj = 0x7FFFFFFF;
    for (int j = t; j < PRE_NMS; j += 1024){
      const unsigned long long v = skey[j];
      if (v > mk || (v == mk && j < mj)){ mk = v; mj = j; }
    }
    #pragma unroll
    for (int off = 32; off > 0; off >>= 1){
      const unsigned long long ok = shfl_down_u64(mk, off);
      const int oj = __shfl_down(mj, off, 64);
      if (ok > mk || (ok == mk && oj < mj)){ mk = ok; mj = oj; }
    }
    if ((t & 63) == 0){ wk[t >> 6] = mk; wj[t >> 6] = mj; }
    __syncthreads();
    if (t == 0){
      unsigned long long bk = wk[0]; int bj = wj[0];
      for (int q = 1; q < 16; ++q){
        if (wk[q] > bk || (wk[q] == bk && wj[q] < bj)){ bk = wk[q]; bj = wj[q]; }
      }
      bk_s = bk; bj_s = bj;
      bbox[0]=selboxd[4*bj+0]; bbox[1]=selboxd[4*bj+1];
      bbox[2]=selboxd[4*bj+2]; bbox[3]=selboxd[4*bj+3];
    }
    __syncthreads();
    const unsigned long long bk = bk_s;
    const int bj = bj_s;
    const bool valid = (bk != KEYNEG);
    const double by1=bbox[0], bx1=bbox[1], by2=bbox[2], bx2=bbox[3];
    const double a1 = fmax(by2-by1, 0.0) * fmax(bx2-bx1, 0.0);
    if (t == 0){
      outp[4*r+0] = valid ? (float)by1 : 0.f;
      outp[4*r+1] = valid ? (float)bx1 : 0.f;
      outp[4*r+2] = valid ? (float)by2 : 0.f;
      outp[4*r+3] = valid ? (float)bx2 : 0.f;
    }
    int jj = 0;
    for (int j = t; j < PRE_NMS; j += 1024){
      const double c0=cb[jj][0], c1=cb[jj][1], c2=cb[jj][2], c3=cb[jj][3];
      ++jj;
      const double yy1 = fmax(by1, c0), xx1 = fmax(bx1, c1);
      const double yy2 = fmin(by2, c2), xx2 = fmin(bx2, c3);
      const double inter = fmax(yy2-yy1, 0.0) * fmax(xx2-xx1, 0.0);
      const double a2 = fmax(c2-c0, 0.0) * fmax(c3-c1, 0.0);
      const double iou = inter / (a1 + a2 - inter + 1e-8);
      if (iou > 0.7 || j == bj) skey[j] = KEYNEG;
    }
  }
}

extern "C" void kernel_launch(void* const* d_in, const int* in_sizes, int n_in,
                              void* d_out, int out_size, void* d_ws, size_t ws_size,
                              hipStream_t stream)
{
  const float* fm   = (const float*)d_in[1];
  const float* amap = (const float*)d_in[2];
  const float* W1   = (const float*)d_in[4];
  const float* b1   = (const float*)d_in[5];
  const float* Wc   = (const float*)d_in[6];
  const float* bc   = (const float*)d_in[7];
  const float* Wr   = (const float*)d_in[8];
  const float* br   = (const float*)d_in[9];
  float* out = (float*)d_out;

  char* base = (char*)d_ws;
  double* scored              = (double*)(base + 0);           // 144000 d
  double* regd                = (double*)(base + 1152000);     // 576000 d
  double* boxesd              = (double*)(base + 5760000);     // 576000 d
  unsigned long long* nmskey  = (unsigned long long*)(base + 10368000); // 144000 u64
  unsigned* key32             = (unsigned*)(base + 11520000);  // 144000 u32
  double* selboxd             = (double*)(base + 12096000);    // 24000 d
  unsigned long long* selkey  = (unsigned long long*)(base + 12288000); // 6000 u64
  int* eqidx                  = (int*)(base + 12336000);       // 8192 i
  unsigned* hist1             = (unsigned*)(base + 12368768);  // 65536 u
  unsigned* hist2             = (unsigned*)(base + 12630912);  // 65536 u
  int* cnt                    = (int*)(base + 12893056);       // 2 i
  int* meta                   = (int*)(base + 12893064);       // 8 i

  // zero hist1|hist2|cnt (contiguous)
  hipMemsetAsync(hist1, 0, (size_t)(65536 + 65536 + 2) * sizeof(unsigned), stream);

  hipLaunchKernelGGL(conv_head, dim3(1000), dim3(256), 0, stream,
                     fm, W1, b1, Wc, bc, Wr, br, out, scored, regd);
  hipLaunchKernelGGL(decode_kernel, dim3((NANCH + 255)/256), dim3(256), 0, stream,
                     amap, scored, regd, boxesd, key32, nmskey);
  hipLaunchKernelGGL(hist_hi, dim3((NANCH + 255)/256), dim3(256), 0, stream, key32, hist1);
  hipLaunchKernelGGL(scan_hi, dim3(1), dim3(1024), 0, stream, hist1, meta);
  hipLaunchKernelGGL(hist_lo, dim3((NANCH + 255)/256), dim3(256), 0, stream, key32, meta, hist2);
  hipLaunchKernelGGL(scan_lo, dim3(1), dim3(1024), 0, stream, hist2, meta);
  hipLaunchKernelGGL(compact_k, dim3((NANCH + 255)/256), dim3(256), 0, stream,
                     key32, nmskey, boxesd, meta, cnt, selboxd, selkey, eqidx);
  hipLaunchKernelGGL(rankeq, dim3(1), dim3(256), 0, stream,
                     scored, boxesd, nmskey, meta, cnt, eqidx, selboxd, selkey);
  hipLaunchKernelGGL(nms_k, dim3(1), dim3(1024), 0, stream, selboxd, selkey, out + 720000);
}

// Round 3
// 6642.873 us; speedup vs baseline: 1.1127x; 1.1127x over previous
//
#include <hip/hip_runtime.h>
#include <math.h>

#define FHh 100
#define FWw 160
#define CIN 512
#define COUT 512
#define NPIX 16000
#define NANCH 144000
#define PRE_NMS 6000
#define POST_NMS 300
#define EQCAP 8192

// monotonic fp32 -> u32 key
__device__ __forceinline__ unsigned fkey(float x){
  unsigned b = __float_as_uint(x);
  return (b & 0x80000000u) ? ~b : (b | 0x80000000u);
}
// monotonic fp64 -> u64 key
__device__ __forceinline__ unsigned long long dkey(double x){
  unsigned long long u = (unsigned long long)__double_as_longlong(x);
  return (u & 0x8000000000000000ull) ? ~u : (u | 0x8000000000000000ull);
}
__device__ __forceinline__ unsigned long long shfl_u64(unsigned long long x, int lane){
  unsigned lo = (unsigned)x, hi = (unsigned)(x >> 32);
  lo = __shfl(lo, lane, 64);
  hi = __shfl(hi, lane, 64);
  return ((unsigned long long)hi << 32) | lo;
}

// ---------------- weight transpose: W1[tap][ci][co] -> WT2[((tap*128+c4)*512+co)*4+k] ----------------
__global__ __launch_bounds__(256) void wtprep(const float* __restrict__ W1, float* __restrict__ WT2){
  const int o = blockIdx.x*256 + threadIdx.x;
  if (o >= 9*512*512) return;
  const int k  = o & 3;
  const int co = (o >> 2) & 511;
  const int c4 = (o >> 11) & 127;
  const int tap = o >> 18;
  WT2[o] = W1[((size_t)(tap*512 + (c4*4 + k)))*512 + co];
}

// ---------------- head weights: transpose + cvt to f64 ----------------
__global__ __launch_bounds__(256) void hwprep(const float* __restrict__ Wc, const float* __restrict__ Wr,
                                              double* __restrict__ WcT, double* __restrict__ WrT){
  const int gid = blockIdx.x*256 + threadIdx.x;
  if (gid >= 45*512) return;
  const int n = gid >> 9, ci = gid & 511;
  if (n < 9) WcT[(size_t)n*512 + ci] = (double)Wc[ci*9 + n];
  else       WrT[(size_t)(n-9)*512 + ci] = (double)Wr[ci*36 + (n-9)];
}

// ---------------- 3x3 conv 512->512, f64 acc, thread = 4 couts x 16 px ----------------
__device__ __forceinline__ void loadw(const float* __restrict__ wp, int co0, double w[4][4]){
  #pragma unroll
  for (int q = 0; q < 4; ++q){
    const float4 wf = *(const float4*)&wp[(size_t)(co0 + q*64)*4];
    w[q][0]=(double)wf.x; w[q][1]=(double)wf.y; w[q][2]=(double)wf.z; w[q][3]=(double)wf.w;
  }
}
__device__ __forceinline__ void fma16(double acc[4][16], int p, float4 vf, const double w[4][4]){
  const double v0=(double)vf.x, v1=(double)vf.y, v2=(double)vf.z, v3=(double)vf.w;
  #pragma unroll
  for (int q = 0; q < 4; ++q){
    acc[q][p] = fma(v0, w[q][0], acc[q][p]);
    acc[q][p] = fma(v1, w[q][1], acc[q][p]);
    acc[q][p] = fma(v2, w[q][2], acc[q][p]);
    acc[q][p] = fma(v3, w[q][3], acc[q][p]);
  }
}

__global__ __launch_bounds__(256, 2) void conv3(
    const float* __restrict__ fm, const float* __restrict__ WT2,
    const float* __restrict__ b1, double* __restrict__ yd)
{
  const int bid  = blockIdx.x;            // 500 blocks
  const int coh  = bid & 1;               // cout half
  const int tile = bid >> 1;              // 0..249
  const int rseg = tile / 5;
  const int xseg = tile - rseg*5;
  const int t    = threadIdx.x;
  const int cb   = t & 63;
  const int pxs  = t >> 6;                // 0..3
  const int row  = rseg*2 + (pxs >> 1);
  const int xb   = xseg*32 + (pxs & 1)*16;
  const int co0  = coh*256 + cb;          // couts co0 + q*64

  double acc[4][16];
  #pragma unroll
  for (int q = 0; q < 4; ++q)
    #pragma unroll
    for (int p = 0; p < 16; ++p) acc[q][p] = 0.0;

  for (int dy = -1; dy <= 1; ++dy){
    const int yy = row + dy;
    if (yy < 0 || yy >= FHh) continue;      // SAME zero-pad (skip = add exact zeros)
    const float* frow = fm + (size_t)yy * FWw * CIN;
    for (int dx = -1; dx <= 1; ++dx){
      const int tap = (dy+1)*3 + (dx+1);
      const int xlo = xb + dx;
      const float* wtap = WT2 + (size_t)tap * 128 * 2048;
      if (xlo >= 0 && xlo + 15 < FWw){
        const float* f0 = frow + (size_t)xlo * CIN;
        for (int c4 = 0; c4 < 128; ++c4){
          double w[4][4];
          loadw(wtap + (size_t)c4*2048, co0, w);
          #pragma unroll
          for (int p = 0; p < 16; ++p){
            const float4 vf = *(const float4*)&f0[(size_t)p*CIN + c4*4];
            fma16(acc, p, vf, w);
          }
        }
      } else {
        for (int c4 = 0; c4 < 128; ++c4){
          double w[4][4];
          loadw(wtap + (size_t)c4*2048, co0, w);
          #pragma unroll
          for (int p = 0; p < 16; ++p){
            const int xx = xlo + p;
            float4 vf = make_float4(0.f, 0.f, 0.f, 0.f);
            if (xx >= 0 && xx < FWw) vf = *(const float4*)&frow[(size_t)xx*CIN + c4*4];
            fma16(acc, p, vf, w);
          }
        }
      }
    }
  }
  #pragma unroll
  for (int q = 0; q < 4; ++q){
    const double bb = (double)b1[co0 + q*64];
    #pragma unroll
    for (int p = 0; p < 16; ++p){
      yd[((size_t)(row*FWw + xb + p))*CIN + co0 + q*64] = fmax(acc[q][p] + bb, 0.0);
    }
  }
}

// ---------------- 1x1 heads (f64), y tile staged in LDS ----------------
__global__ __launch_bounds__(256) void head2(
    const double* __restrict__ yd, const double* __restrict__ WcT, const float* __restrict__ bc,
    const double* __restrict__ WrT, const float* __restrict__ br,
    float* __restrict__ out, double* __restrict__ scored, double* __restrict__ regd)
{
  __shared__ double yl[8192];          // 16 px x 512, 64 KB
  const int bid = blockIdx.x, t = threadIdx.x;
  const double2* src = (const double2*)(yd + (size_t)bid * 8192);
  double2* dst = (double2*)yl;
  for (int j = t; j < 4096; j += 256) dst[j] = src[j];
  __syncthreads();
  for (int j = t; j < 720; j += 256){
    const int p = j / 45, n = j - p*45;
    const double* yr = yl + p*512;
    double s = 0.0;
    if (n < 9){
      const double* w = WcT + (size_t)n*512;
      for (int ci = 0; ci < 512; ++ci) s = fma(yr[ci], w[ci], s);
      s += (double)bc[n];
      const double sig = 1.0 / (1.0 + exp(-s));
      const int gi = (bid*16 + p)*9 + n;
      out[gi] = (float)sig;
      scored[gi] = sig;
    } else {
      const int m = n - 9;
      const double* w = WrT + (size_t)m*512;
      for (int ci = 0; ci < 512; ++ci) s = fma(yr[ci], w[ci], s);
      s += (double)br[m];
      const int gi = (bid*16 + p)*36 + m;
      out[144000 + gi] = (float)s;
      regd[gi] = s;
    }
  }
}

// ---------------- decode + clip + min-size (all f64) ----------------
__global__ __launch_bounds__(256) void decode_kernel(
    const float* __restrict__ amap, const double* __restrict__ scored,
    const double* __restrict__ regd, double* __restrict__ boxesd,
    unsigned* __restrict__ key32, unsigned long long* __restrict__ nmskey)
{
  const int i = blockIdx.x*256 + threadIdx.x;
  if (i >= NANCH) return;
  const double a0=(double)amap[4*i+0], a1=(double)amap[4*i+1];
  const double a2=(double)amap[4*i+2], a3=(double)amap[4*i+3];
  const double d0=regd[4*i+0], d1=regd[4*i+1], d2=regd[4*i+2], d3=regd[4*i+3];
  const double ah = a2 - a0, aw = a3 - a1;
  const double cy = a0 + 0.5*ah + d0*ah;
  const double cx = a1 + 0.5*aw + d1*aw;
  const double h = ah * exp(d2), w = aw * exp(d3);
  double y1 = cy - 0.5*h, x1 = cx - 0.5*w, y2 = cy + 0.5*h, x2 = cx + 0.5*w;
  y1 = fmax(y1, 0.0); x1 = fmax(x1, 0.0);
  y2 = fmin(y2, 1600.0); x2 = fmin(x2, 2560.0);
  boxesd[4*i+0]=y1; boxesd[4*i+1]=x1; boxesd[4*i+2]=y2; boxesd[4*i+3]=x2;
  const double obj = scored[i];
  const bool ok = (y2 - y1 >= 16.0) && (x2 - x1 >= 16.0);
  key32[i] = fkey((float)obj);
  nmskey[i] = ok ? dkey(obj) : dkey(-1e9);
}

// ---------------- top-6000 radix select on f32-rounded keys ----------------
__global__ __launch_bounds__(256) void hist_hi(const unsigned* __restrict__ key, unsigned* __restrict__ hist){
  const int i = blockIdx.x*256 + threadIdx.x;
  if (i < NANCH) atomicAdd(&hist[key[i] >> 16], 1u);
}

__global__ __launch_bounds__(1024) void scan_hi(const unsigned* __restrict__ hist, int* __restrict__ meta){
  __shared__ unsigned part[1024];
  const int t = threadIdx.x;
  unsigned s = 0;
  for (int j = 0; j < 64; ++j) s += hist[65535 - (t*64 + j)];
  part[t] = s;
  __syncthreads();
  for (int off = 1; off < 1024; off <<= 1){
    unsigned v = (t >= off) ? part[t - off] : 0u;
    __syncthreads();
    part[t] += v;
    __syncthreads();
  }
  const unsigned incl = part[t], excl = incl - s;
  if (excl < PRE_NMS && incl >= PRE_NMS){
    unsigned cum = excl;
    for (int j = 0; j < 64; ++j){
      const int bin = 65535 - (t*64 + j);
      const unsigned c = hist[bin];
      if (cum + c >= PRE_NMS){ meta[0] = bin; meta[1] = (int)cum; break; }
      cum += c;
    }
  }
}

__global__ __launch_bounds__(256) void hist_lo(const unsigned* __restrict__ key,
                                               const int* __restrict__ meta, unsigned* __restrict__ hist){
  const int i = blockIdx.x*256 + threadIdx.x;
  if (i < NANCH){
    const unsigned k = key[i];
    if ((int)(k >> 16) == meta[0]) atomicAdd(&hist[k & 0xFFFFu], 1u);
  }
}

__global__ __launch_bounds__(1024) void scan_lo(const unsigned* __restrict__ hist, int* __restrict__ meta){
  __shared__ unsigned part[1024];
  const int t = threadIdx.x;
  const unsigned G0 = (unsigned)meta[1];
  unsigned s = 0;
  for (int j = 0; j < 64; ++j) s += hist[65535 - (t*64 + j)];
  part[t] = s;
  __syncthreads();
  for (int off = 1; off < 1024; off <<= 1){
    unsigned v = (t >= off) ? part[t - off] : 0u;
    __syncthreads();
    part[t] += v;
    __syncthreads();
  }
  const unsigned incl = G0 + part[t], excl = incl - s;
  if (excl < PRE_NMS && incl >= PRE_NMS){
    unsigned cum = excl;
    for (int j = 0; j < 64; ++j){
      const int bin = 65535 - (t*64 + j);
      const unsigned c = hist[bin];
      if (cum + c >= PRE_NMS){
        meta[2] = (int)(((unsigned)meta[0] << 16) | (unsigned)bin);
        meta[3] = (int)cum;
        meta[4] = PRE_NMS - (int)cum;
        break;
      }
      cum += c;
    }
  }
}

__global__ __launch_bounds__(256) void compact_k(
    const unsigned* __restrict__ key, const unsigned long long* __restrict__ nmskey,
    const double* __restrict__ boxesd, const int* __restrict__ meta,
    int* __restrict__ cnt, double* __restrict__ selboxd,
    unsigned long long* __restrict__ selkey, int* __restrict__ eqidx)
{
  const int i = blockIdx.x*256 + threadIdx.x;
  if (i >= NANCH) return;
  const unsigned k = key[i];
  const unsigned T = (unsigned)meta[2];
  if (k > T){
    const int s = atomicAdd(&cnt[0], 1);
    selboxd[4*s+0]=boxesd[4*i+0]; selboxd[4*s+1]=boxesd[4*i+1];
    selboxd[4*s+2]=boxesd[4*i+2]; selboxd[4*s+3]=boxesd[4*i+3];
    selkey[s] = nmskey[i];
  } else if (k == T){
    const int e = atomicAdd(&cnt[1], 1);
    if (e < EQCAP) eqidx[e] = i;
  }
}

__global__ __launch_bounds__(256) void rankeq(
    const double* __restrict__ scored, const double* __restrict__ boxesd,
    const unsigned long long* __restrict__ nmskey,
    const int* __restrict__ meta, const int* __restrict__ cnt,
    const int* __restrict__ eqidx, double* __restrict__ selboxd,
    unsigned long long* __restrict__ selkey)
{
  __shared__ int eq[EQCAP];
  const int t = threadIdx.x;
  int E = cnt[1]; if (E > EQCAP) E = EQCAP;
  const int R = meta[4], G2 = meta[3];
  for (int j = t; j < E; j += 256) eq[j] = eqidx[j];
  __syncthreads();
  for (int j = t; j < E; j += 256){
    const int my = eq[j];
    const double smy = scored[my];
    int rank = 0;
    for (int k2 = 0; k2 < E; ++k2){
      const int ok = eq[k2];
      const double sk = scored[ok];
      rank += ((sk > smy) || (sk == smy && ok < my)) ? 1 : 0;
    }
    if (rank < R){
      const int s = G2 + rank;
      selboxd[4*s+0]=boxesd[4*my+0]; selboxd[4*s+1]=boxesd[4*my+1];
      selboxd[4*s+2]=boxesd[4*my+2]; selboxd[4*s+3]=boxesd[4*my+3];
      selkey[s] = nmskey[my];
    }
  }
}

// ---------------- bitonic sort of 6000 keys (desc; tie -> lower slot) ----------------
// keys in 64 KB LDS; positions in global (volatile, bypasses L1 across barriers)
__global__ __launch_bounds__(1024) void sort_sel(
    const unsigned long long* __restrict__ selkey, const double* __restrict__ selboxd,
    volatile unsigned* gpos, unsigned long long* __restrict__ skeys, double* __restrict__ sboxd)
{
  __shared__ unsigned long long sk[8192];
  const int t = threadIdx.x;
  #pragma unroll
  for (int e = 0; e < 8; ++e){
    const int i = e*1024 + t;
    sk[i] = (i < PRE_NMS) ? selkey[i] : 0ull;
    gpos[i] = (unsigned)i;
  }
  __syncthreads();
  for (int k = 2; k <= 8192; k <<= 1){
    for (int j = k >> 1; j > 0; j >>= 1){
      #pragma unroll 1
      for (int e = 0; e < 8; ++e){
        const int i = e*1024 + t;
        const int p = i ^ j;
        if (p > i){
          const unsigned long long ka = sk[i], kb = sk[p];
          const unsigned pa = gpos[i], pb = gpos[p];
          const bool agtb = (ka > kb) || (ka == kb && pa < pb);
          const bool desc = ((i & k) == 0);
          if (desc ? !agtb : agtb){
            sk[i] = kb; sk[p] = ka;
            gpos[i] = pb; gpos[p] = pa;
          }
        }
      }
      __syncthreads();
    }
  }
  #pragma unroll 1
  for (int e = 0; e < 8; ++e){
    const int i = e*1024 + t;
    if (i < PRE_NMS){
      skeys[i] = sk[i];
      const int s = (int)gpos[i];
      sboxd[(size_t)i*4+0] = selboxd[(size_t)s*4+0];
      sboxd[(size_t)i*4+1] = selboxd[(size_t)s*4+1];
      sboxd[(size_t)i*4+2] = selboxd[(size_t)s*4+2];
      sboxd[(size_t)i*4+3] = selboxd[(size_t)s*4+3];
    }
  }
}

// ---------------- 6000x6000 IOU suppression bitmap (rank-indexed) ----------------
__global__ __launch_bounds__(256) void iou_bitmap(
    const double* __restrict__ sboxd, unsigned long long* __restrict__ rowbits)
{
  __shared__ double cbx[4096];           // 1024 col boxes
  const int g = blockIdx.y;              // 0..5 word-groups
  const int r0 = blockIdx.x * 16;
  const int t = threadIdx.x;
  const int cbase = g * 1024;
  for (int e = t; e < 4096; e += 256){
    const int bi = cbase + (e >> 2);
    cbx[e] = (bi < PRE_NMS) ? sboxd[(size_t)bi*4 + (e & 3)] : 0.0;
  }
  __syncthreads();
  const int r = r0 + (t >> 4);
  const int w = t & 15;
  const double by1 = sboxd[(size_t)r*4+0], bx1 = sboxd[(size_t)r*4+1];
  const double by2 = sboxd[(size_t)r*4+2], bx2 = sboxd[(size_t)r*4+3];
  const double a1 = fmax(by2-by1, 0.0) * fmax(bx2-bx1, 0.0);
  unsigned long long bits = 0ull;
  for (int b = 0; b < 64; ++b){
    const int bcol = (b + w) & 63;       // bank-swizzled column within word
    const int j = cbase + w*64 + bcol;
    if (j < PRE_NMS){
      const int ce = (w*64 + bcol)*4;
      const double c0 = cbx[ce+0], c1 = cbx[ce+1], c2 = cbx[ce+2], c3 = cbx[ce+3];
      const double yy1 = fmax(by1, c0), xx1 = fmax(bx1, c1);
      const double yy2 = fmin(by2, c2), xx2 = fmin(bx2, c3);
      const double inter = fmax(yy2-yy1, 0.0) * fmax(xx2-xx1, 0.0);
      const double a2 = fmax(c2-c0, 0.0) * fmax(c3-c1, 0.0);
      const double iou = inter / (a1 + a2 - inter + 1e-8);
      if (iou > 0.7) bits |= (1ull << bcol);
    }
  }
  rowbits[(size_t)r*128 + g*16 + w] = bits;   // words 94/95 are j>=6000 -> 0, never read
}

// ---------------- greedy scan over sorted order with suppression bitmap ----------------
__global__ __launch_bounds__(64) void greedy(
    const unsigned long long* __restrict__ skeys, const double* __restrict__ sboxd,
    const unsigned long long* __restrict__ rowbits, float* __restrict__ outp)
{
  const int t = threadIdx.x;
  unsigned long long s0 = 0ull, s1 = 0ull;   // lane t owns words t and 64+t
  const unsigned long long KEYTH = dkey(-5.0e8);   // valid iff score > NEG*0.5
  int emitted = 0;
  for (int i = 0; i < PRE_NMS && emitted < POST_NMS; ++i){
    const unsigned long long ki = skeys[i];
    if (ki <= KEYTH) break;                  // rest invalid -> zero-fill
    const int w = i >> 6, b = i & 63;
    const unsigned long long w0 = shfl_u64(s0, w & 63);
    const unsigned long long w1 = shfl_u64(s1, (w - 64) & 63);
    const unsigned long long word = (w < 64) ? w0 : w1;
    if (!((word >> b) & 1ull)){
      if (t < 4) outp[4*emitted + t] = (float)sboxd[(size_t)i*4 + t];
      s0 |= rowbits[(size_t)i*128 + t];
      if (t < 30) s1 |= rowbits[(size_t)i*128 + 64 + t];
      ++emitted;
    }
  }
  for (int r = emitted; r < POST_NMS; ++r)
    if (t < 4) outp[4*r + t] = 0.f;
}

extern "C" void kernel_launch(void* const* d_in, const int* in_sizes, int n_in,
                              void* d_out, int out_size, void* d_ws, size_t ws_size,
                              hipStream_t stream)
{
  const float* fm   = (const float*)d_in[1];
  const float* amap = (const float*)d_in[2];
  const float* W1   = (const float*)d_in[4];
  const float* b1   = (const float*)d_in[5];
  const float* Wc   = (const float*)d_in[6];
  const float* bc   = (const float*)d_in[7];
  const float* Wr   = (const float*)d_in[8];
  const float* br   = (const float*)d_in[9];
  float* out = (float*)d_out;

  char* base = (char*)d_ws;
  double* yd                  = (double*)(base + 0);                  // 65,536,000
  float* WT2                  = (float*)(base + 65536000);            //  9,437,184
  double* WcT                 = (double*)(base + 74973184);           //     36,864
  double* WrT                 = (double*)(base + 75010048);           //    147,456
  double* scored              = (double*)(base + 75157504);           //  1,152,000
  double* regd                = (double*)(base + 76309504);           //  4,608,000
  double* boxesd              = (double*)(base + 80917504);           //  4,608,000
  unsigned long long* nmskey  = (unsigned long long*)(base + 85525504); // 1,152,000
  unsigned* key32             = (unsigned*)(base + 86677504);         //    576,000
  double* selboxd             = (double*)(base + 87253504);           //    192,000
  unsigned long long* selkey  = (unsigned long long*)(base + 87445504); //   48,000
  unsigned long long* skeys   = (unsigned long long*)(base + 87493504); //   65,536
  double* sboxd               = (double*)(base + 87559040);           //    192,000
  unsigned* gpos              = (unsigned*)(base + 87751040);         //     32,768
  unsigned long long* rowbits = (unsigned long long*)(base + 87783808); // 6,144,000
  int* eqidx                  = (int*)(base + 93927808);              //     32,768
  unsigned* hist1             = (unsigned*)(base + 93960576);         //    262,144
  unsigned* hist2             = (unsigned*)(base + 94222720);         //    262,144
  int* cnt                    = (int*)(base + 94484864);              //          8
  int* meta                   = (int*)(base + 94484872);              //         32

  // zero hist1|hist2|cnt|meta (contiguous)
  hipMemsetAsync(hist1, 0, (size_t)524328, stream);

  hipLaunchKernelGGL(wtprep, dim3((9*512*512 + 255)/256), dim3(256), 0, stream, W1, WT2);
  hipLaunchKernelGGL(hwprep, dim3((45*512 + 255)/256), dim3(256), 0, stream, Wc, Wr, WcT, WrT);
  hipLaunchKernelGGL(conv3, dim3(500), dim3(256), 0, stream, fm, WT2, b1, yd);
  hipLaunchKernelGGL(head2, dim3(1000), dim3(256), 0, stream, yd, WcT, bc, WrT, br, out, scored, regd);
  hipLaunchKernelGGL(decode_kernel, dim3((NANCH + 255)/256), dim3(256), 0, stream,
                     amap, scored, regd, boxesd, key32, nmskey);
  hipLaunchKernelGGL(hist_hi, dim3((NANCH + 255)/256), dim3(256), 0, stream, key32, hist1);
  hipLaunchKernelGGL(scan_hi, dim3(1), dim3(1024), 0, stream, hist1, meta);
  hipLaunchKernelGGL(hist_lo, dim3((NANCH + 255)/256), dim3(256), 0, stream, key32, meta, hist2);
  hipLaunchKernelGGL(scan_lo, dim3(1), dim3(1024), 0, stream, hist2, meta);
  hipLaunchKernelGGL(compact_k, dim3((NANCH + 255)/256), dim3(256), 0, stream,
                     key32, nmskey, boxesd, meta, cnt, selboxd, selkey, eqidx);
  hipLaunchKernelGGL(rankeq, dim3(1), dim3(256), 0, stream,
                     scored, boxesd, nmskey, meta, cnt, eqidx, selboxd, selkey);
  hipLaunchKernelGGL(sort_sel, dim3(1), dim3(1024), 0, stream,
                     selkey, selboxd, (volatile unsigned*)gpos, skeys, sboxd);
  hipLaunchKernelGGL(iou_bitmap, dim3(375, 6), dim3(256), 0, stream, sboxd, rowbits);
  hipLaunchKernelGGL(greedy, dim3(1), dim3(64), 0, stream, skeys, sboxd, rowbits, out + 720000);
}

// Round 4
// 4118.528 us; speedup vs baseline: 1.7947x; 1.6129x over previous
//
#include <hip/hip_runtime.h>
#include <math.h>

#define FHh 100
#define FWw 160
#define CIN 512
#define COUT 512
#define NPIX 16000
#define NANCH 144000
#define PRE_NMS 6000
#define POST_NMS 300
#define EQCAP 8192

// monotonic fp32 -> u32 key
__device__ __forceinline__ unsigned fkey(float x){
  unsigned b = __float_as_uint(x);
  return (b & 0x80000000u) ? ~b : (b | 0x80000000u);
}
// monotonic fp64 -> u64 key
__device__ __forceinline__ unsigned long long dkey(double x){
  unsigned long long u = (unsigned long long)__double_as_longlong(x);
  return (u & 0x8000000000000000ull) ? ~u : (u | 0x8000000000000000ull);
}
__device__ __forceinline__ unsigned long long shfl_u64(unsigned long long x, int lane){
  unsigned lo = (unsigned)x, hi = (unsigned)(x >> 32);
  lo = __shfl(lo, lane, 64);
  hi = __shfl(hi, lane, 64);
  return ((unsigned long long)hi << 32) | lo;
}

// ---------------- weight transpose: W1[tap][ci][co] -> WT2[((tap*128+c4)*512+co)*4+k] ----------------
__global__ __launch_bounds__(256) void wtprep(const float* __restrict__ W1, float* __restrict__ WT2){
  const int o = blockIdx.x*256 + threadIdx.x;
  if (o >= 9*512*512) return;
  const int k  = o & 3;
  const int co = (o >> 2) & 511;
  const int c4 = (o >> 11) & 127;
  const int tap = o >> 18;
  WT2[o] = W1[((size_t)(tap*512 + (c4*4 + k)))*512 + co];
}

// ---------------- head weights: transpose + cvt to f64 ----------------
__global__ __launch_bounds__(256) void hwprep(const float* __restrict__ Wc, const float* __restrict__ Wr,
                                              double* __restrict__ WcT, double* __restrict__ WrT){
  const int gid = blockIdx.x*256 + threadIdx.x;
  if (gid >= 45*512) return;
  const int n = gid >> 9, ci = gid & 511;
  if (n < 9) WcT[(size_t)n*512 + ci] = (double)Wc[ci*9 + n];
  else       WrT[(size_t)(n-9)*512 + ci] = (double)Wr[ci*36 + (n-9)];
}

// ---------------- fm f32 -> f64 copy ----------------
__global__ __launch_bounds__(256) void fmprep(const float* __restrict__ fm, double* __restrict__ fmd){
  const int i = blockIdx.x*256 + threadIdx.x;     // i < NPIX*128 (float4 granules)
  if (i >= NPIX*128) return;
  const float4 v = ((const float4*)fm)[i];
  double2* d = (double2*)(fmd + (size_t)i*4);
  d[0] = make_double2((double)v.x, (double)v.y);
  d[1] = make_double2((double)v.z, (double)v.w);
}

// ---------------- 3x3 conv 512->512, f64 acc, thread = 2 couts x 8 px ----------------
// grid 2000 = 500 row-tiles(32px) x 4 co-groups(128); 4 waves/SIMD via launch_bounds(256,4)
template<bool F64FM>
__global__ __launch_bounds__(256, 4) void conv3t(
    const float* __restrict__ fm, const double* __restrict__ fmd,
    const float* __restrict__ WT2, const float* __restrict__ b1, double* __restrict__ yd)
{
  const int bid  = blockIdx.x;
  const int tile = bid >> 2;              // 0..499
  const int coh  = bid & 3;               // co-group of 128
  const int row  = tile / 5;
  const int xseg = tile - row*5;
  const int t    = threadIdx.x;
  const int lane = t & 63;
  const int wg   = __builtin_amdgcn_readfirstlane(t >> 6);   // wave-uniform px-group
  const int xg   = xseg*32 + wg*8;        // 8 px starting here
  const int co0  = coh*128 + lane;        // couts co0, co0+64

  double acc[2][8];
  #pragma unroll
  for (int g = 0; g < 2; ++g)
    #pragma unroll
    for (int p = 0; p < 8; ++p) acc[g][p] = 0.0;

  for (int dy = -1; dy <= 1; ++dy){
    const int yy = row + dy;
    if (yy < 0 || yy >= FHh) continue;         // SAME zero-pad
    const double* frd = fmd + (size_t)yy * FWw * CIN;
    const float*  frf = fm  + (size_t)yy * FWw * CIN;
    for (int dx = -1; dx <= 1; ++dx){
      const int tap = (dy+1)*3 + (dx+1);
      const int x0 = xg + dx;
      const bool interior = (x0 >= 0) && (x0 + 7 < FWw);
      const float* wtap = WT2 + (size_t)tap * 262144;
      #pragma unroll 1
      for (int c4 = 0; c4 < 128; ++c4){
        const float4 fa = *(const float4*)&wtap[((size_t)c4*512 + co0)*4];
        const float4 fb = *(const float4*)&wtap[((size_t)c4*512 + co0 + 64)*4];
        const double wa0=(double)fa.x, wa1=(double)fa.y, wa2=(double)fa.z, wa3=(double)fa.w;
        const double wb0=(double)fb.x, wb1=(double)fb.y, wb2=(double)fb.z, wb3=(double)fb.w;
        #pragma unroll
        for (int p = 0; p < 8; ++p){
          const int xx = x0 + p;
          if (!interior && (xx < 0 || xx >= FWw)) continue;   // exact zero tap
          double v0, v1, v2, v3;
          if (F64FM){
            const double2 a = *(const double2*)&frd[(size_t)xx*CIN + c4*4];
            const double2 b2 = *(const double2*)&frd[(size_t)xx*CIN + c4*4 + 2];
            v0=a.x; v1=a.y; v2=b2.x; v3=b2.y;
          } else {
            const float4 vf = *(const float4*)&frf[(size_t)xx*CIN + c4*4];
            v0=(double)vf.x; v1=(double)vf.y; v2=(double)vf.z; v3=(double)vf.w;
          }
          acc[0][p] = fma(v0, wa0, acc[0][p]);
          acc[0][p] = fma(v1, wa1, acc[0][p]);
          acc[0][p] = fma(v2, wa2, acc[0][p]);
          acc[0][p] = fma(v3, wa3, acc[0][p]);
          acc[1][p] = fma(v0, wb0, acc[1][p]);
          acc[1][p] = fma(v1, wb1, acc[1][p]);
          acc[1][p] = fma(v2, wb2, acc[1][p]);
          acc[1][p] = fma(v3, wb3, acc[1][p]);
        }
      }
    }
  }
  #pragma unroll
  for (int g = 0; g < 2; ++g){
    const double bb = (double)b1[co0 + g*64];
    #pragma unroll
    for (int p = 0; p < 8; ++p){
      yd[((size_t)(row*FWw + xg + p))*CIN + co0 + g*64] = fmax(acc[g][p] + bb, 0.0);
    }
  }
}

// ---------------- 1x1 heads (f64), y tile staged in LDS ----------------
__global__ __launch_bounds__(256) void head2(
    const double* __restrict__ yd, const double* __restrict__ WcT, const float* __restrict__ bc,
    const double* __restrict__ WrT, const float* __restrict__ br,
    float* __restrict__ out, double* __restrict__ scored, double* __restrict__ regd)
{
  __shared__ double yl[8192];          // 16 px x 512, 64 KB
  const int bid = blockIdx.x, t = threadIdx.x;
  const double2* src = (const double2*)(yd + (size_t)bid * 8192);
  double2* dst = (double2*)yl;
  for (int j = t; j < 4096; j += 256) dst[j] = src[j];
  __syncthreads();
  for (int j = t; j < 720; j += 256){
    const int p = j / 45, n = j - p*45;
    const double* yr = yl + p*512;
    double s0 = 0.0, s1 = 0.0, s2 = 0.0, s3 = 0.0;
    if (n < 9){
      const double* w = WcT + (size_t)n*512;
      for (int ci = 0; ci < 512; ci += 4){
        s0 = fma(yr[ci+0], w[ci+0], s0);
        s1 = fma(yr[ci+1], w[ci+1], s1);
        s2 = fma(yr[ci+2], w[ci+2], s2);
        s3 = fma(yr[ci+3], w[ci+3], s3);
      }
      const double s = ((s0+s1)+(s2+s3)) + (double)bc[n];
      const double sig = 1.0 / (1.0 + exp(-s));
      const int gi = (bid*16 + p)*9 + n;
      out[gi] = (float)sig;
      scored[gi] = sig;
    } else {
      const int m = n - 9;
      const double* w = WrT + (size_t)m*512;
      for (int ci = 0; ci < 512; ci += 4){
        s0 = fma(yr[ci+0], w[ci+0], s0);
        s1 = fma(yr[ci+1], w[ci+1], s1);
        s2 = fma(yr[ci+2], w[ci+2], s2);
        s3 = fma(yr[ci+3], w[ci+3], s3);
      }
      const double s = ((s0+s1)+(s2+s3)) + (double)br[m];
      const int gi = (bid*16 + p)*36 + m;
      out[144000 + gi] = (float)s;
      regd[gi] = s;
    }
  }
}

// ---------------- decode + clip + min-size (all f64) ----------------
__global__ __launch_bounds__(256) void decode_kernel(
    const float* __restrict__ amap, const double* __restrict__ scored,
    const double* __restrict__ regd, double* __restrict__ boxesd,
    unsigned* __restrict__ key32, unsigned long long* __restrict__ nmskey)
{
  const int i = blockIdx.x*256 + threadIdx.x;
  if (i >= NANCH) return;
  const double a0=(double)amap[4*i+0], a1=(double)amap[4*i+1];
  const double a2=(double)amap[4*i+2], a3=(double)amap[4*i+3];
  const double d0=regd[4*i+0], d1=regd[4*i+1], d2=regd[4*i+2], d3=regd[4*i+3];
  const double ah = a2 - a0, aw = a3 - a1;
  const double cy = a0 + 0.5*ah + d0*ah;
  const double cx = a1 + 0.5*aw + d1*aw;
  const double h = ah * exp(d2), w = aw * exp(d3);
  double y1 = cy - 0.5*h, x1 = cx - 0.5*w, y2 = cy + 0.5*h, x2 = cx + 0.5*w;
  y1 = fmax(y1, 0.0); x1 = fmax(x1, 0.0);
  y2 = fmin(y2, 1600.0); x2 = fmin(x2, 2560.0);
  boxesd[4*i+0]=y1; boxesd[4*i+1]=x1; boxesd[4*i+2]=y2; boxesd[4*i+3]=x2;
  const double obj = scored[i];
  const bool ok = (y2 - y1 >= 16.0) && (x2 - x1 >= 16.0);
  key32[i] = fkey((float)obj);
  nmskey[i] = ok ? dkey(obj) : dkey(-1e9);
}

// ---------------- top-6000 radix select on f32-rounded keys ----------------
__global__ __launch_bounds__(256) void hist_hi(const unsigned* __restrict__ key, unsigned* __restrict__ hist){
  const int i = blockIdx.x*256 + threadIdx.x;
  if (i < NANCH) atomicAdd(&hist[key[i] >> 16], 1u);
}

__global__ __launch_bounds__(1024) void scan_hi(const unsigned* __restrict__ hist, int* __restrict__ meta){
  __shared__ unsigned part[1024];
  const int t = threadIdx.x;
  unsigned s = 0;
  for (int j = 0; j < 64; ++j) s += hist[65535 - (t*64 + j)];
  part[t] = s;
  __syncthreads();
  for (int off = 1; off < 1024; off <<= 1){
    unsigned v = (t >= off) ? part[t - off] : 0u;
    __syncthreads();
    part[t] += v;
    __syncthreads();
  }
  const unsigned incl = part[t], excl = incl - s;
  if (excl < PRE_NMS && incl >= PRE_NMS){
    unsigned cum = excl;
    for (int j = 0; j < 64; ++j){
      const int bin = 65535 - (t*64 + j);
      const unsigned c = hist[bin];
      if (cum + c >= PRE_NMS){ meta[0] = bin; meta[1] = (int)cum; break; }
      cum += c;
    }
  }
}

__global__ __launch_bounds__(256) void hist_lo(const unsigned* __restrict__ key,
                                               const int* __restrict__ meta, unsigned* __restrict__ hist){
  const int i = blockIdx.x*256 + threadIdx.x;
  if (i < NANCH){
    const unsigned k = key[i];
    if ((int)(k >> 16) == meta[0]) atomicAdd(&hist[k & 0xFFFFu], 1u);
  }
}

__global__ __launch_bounds__(1024) void scan_lo(const unsigned* __restrict__ hist, int* __restrict__ meta){
  __shared__ unsigned part[1024];
  const int t = threadIdx.x;
  const unsigned G0 = (unsigned)meta[1];
  unsigned s = 0;
  for (int j = 0; j < 64; ++j) s += hist[65535 - (t*64 + j)];
  part[t] = s;
  __syncthreads();
  for (int off = 1; off < 1024; off <<= 1){
    unsigned v = (t >= off) ? part[t - off] : 0u;
    __syncthreads();
    part[t] += v;
    __syncthreads();
  }
  const unsigned incl = G0 + part[t], excl = incl - s;
  if (excl < PRE_NMS && incl >= PRE_NMS){
    unsigned cum = excl;
    for (int j = 0; j < 64; ++j){
      const int bin = 65535 - (t*64 + j);
      const unsigned c = hist[bin];
      if (cum + c >= PRE_NMS){
        meta[2] = (int)(((unsigned)meta[0] << 16) | (unsigned)bin);
        meta[3] = (int)cum;
        meta[4] = PRE_NMS - (int)cum;
        break;
      }
      cum += c;
    }
  }
}

__global__ __launch_bounds__(256) void compact_k(
    const unsigned* __restrict__ key, const unsigned long long* __restrict__ nmskey,
    const double* __restrict__ boxesd, const int* __restrict__ meta,
    int* __restrict__ cnt, double* __restrict__ selboxd,
    unsigned long long* __restrict__ selkey, int* __restrict__ eqidx)
{
  const int i = blockIdx.x*256 + threadIdx.x;
  if (i >= NANCH) return;
  const unsigned k = key[i];
  const unsigned T = (unsigned)meta[2];
  if (k > T){
    const int s = atomicAdd(&cnt[0], 1);
    selboxd[4*s+0]=boxesd[4*i+0]; selboxd[4*s+1]=boxesd[4*i+1];
    selboxd[4*s+2]=boxesd[4*i+2]; selboxd[4*s+3]=boxesd[4*i+3];
    selkey[s] = nmskey[i];
  } else if (k == T){
    const int e = atomicAdd(&cnt[1], 1);
    if (e < EQCAP) eqidx[e] = i;
  }
}

__global__ __launch_bounds__(256) void rankeq(
    const double* __restrict__ scored, const double* __restrict__ boxesd,
    const unsigned long long* __restrict__ nmskey,
    const int* __restrict__ meta, const int* __restrict__ cnt,
    const int* __restrict__ eqidx, double* __restrict__ selboxd,
    unsigned long long* __restrict__ selkey)
{
  __shared__ int eq[EQCAP];
  const int t = threadIdx.x;
  int E = cnt[1]; if (E > EQCAP) E = EQCAP;
  const int R = meta[4], G2 = meta[3];
  for (int j = t; j < E; j += 256) eq[j] = eqidx[j];
  __syncthreads();
  for (int j = t; j < E; j += 256){
    const int my = eq[j];
    const double smy = scored[my];
    int rank = 0;
    for (int k2 = 0; k2 < E; ++k2){
      const int ok = eq[k2];
      const double sk = scored[ok];
      rank += ((sk > smy) || (sk == smy && ok < my)) ? 1 : 0;
    }
    if (rank < R){
      const int s = G2 + rank;
      selboxd[4*s+0]=boxesd[4*my+0]; selboxd[4*s+1]=boxesd[4*my+1];
      selboxd[4*s+2]=boxesd[4*my+2]; selboxd[4*s+3]=boxesd[4*my+3];
      selkey[s] = nmskey[my];
    }
  }
}

// ---------------- rank-by-counting scatter (replaces bitonic sort) ----------------
// tie-break by compact slot index (matches prior passing semantics; real-score ties don't occur)
__global__ __launch_bounds__(256) void rank_scatter(
    const unsigned long long* __restrict__ selkey, const double* __restrict__ selboxd,
    unsigned long long* __restrict__ skeys, double* __restrict__ sboxd)
{
  __shared__ unsigned long long k[PRE_NMS];
  const int t = threadIdx.x;
  for (int j = t; j < PRE_NMS; j += 256) k[j] = selkey[j];
  __syncthreads();
  const int j = blockIdx.x*256 + t;
  if (j >= PRE_NMS) return;
  const unsigned long long kj = k[j];
  int r = 0;
  for (int i = 0; i < PRE_NMS; i += 4){
    r += (int)((k[i+0] > kj) || (k[i+0] == kj && (i+0) < j));
    r += (int)((k[i+1] > kj) || (k[i+1] == kj && (i+1) < j));
    r += (int)((k[i+2] > kj) || (k[i+2] == kj && (i+2) < j));
    r += (int)((k[i+3] > kj) || (k[i+3] == kj && (i+3) < j));
  }
  skeys[r] = kj;
  sboxd[(size_t)r*4+0] = selboxd[(size_t)j*4+0];
  sboxd[(size_t)r*4+1] = selboxd[(size_t)j*4+1];
  sboxd[(size_t)r*4+2] = selboxd[(size_t)j*4+2];
  sboxd[(size_t)r*4+3] = selboxd[(size_t)j*4+3];
}

// ---------------- 6000x6000 IOU suppression bitmap (rank-indexed) ----------------
__global__ __launch_bounds__(256) void iou_bitmap(
    const double* __restrict__ sboxd, unsigned long long* __restrict__ rowbits)
{
  __shared__ double cbx[4096];           // 1024 col boxes
  const int g = blockIdx.y;              // 0..5 word-groups
  const int r0 = blockIdx.x * 16;
  const int t = threadIdx.x;
  const int cbase = g * 1024;
  for (int e = t; e < 4096; e += 256){
    const int bi = cbase + (e >> 2);
    cbx[e] = (bi < PRE_NMS) ? sboxd[(size_t)bi*4 + (e & 3)] : 0.0;
  }
  __syncthreads();
  const int r = r0 + (t >> 4);
  const int w = t & 15;
  const double by1 = sboxd[(size_t)r*4+0], bx1 = sboxd[(size_t)r*4+1];
  const double by2 = sboxd[(size_t)r*4+2], bx2 = sboxd[(size_t)r*4+3];
  const double a1 = fmax(by2-by1, 0.0) * fmax(bx2-bx1, 0.0);
  unsigned long long bits = 0ull;
  for (int b = 0; b < 64; ++b){
    const int bcol = (b + w) & 63;
    const int j = cbase + w*64 + bcol;
    if (j < PRE_NMS){
      const int ce = (w*64 + bcol)*4;
      const double c0 = cbx[ce+0], c1 = cbx[ce+1], c2 = cbx[ce+2], c3 = cbx[ce+3];
      const double yy1 = fmax(by1, c0), xx1 = fmax(bx1, c1);
      const double yy2 = fmin(by2, c2), xx2 = fmin(bx2, c3);
      const double inter = fmax(yy2-yy1, 0.0) * fmax(xx2-xx1, 0.0);
      const double a2 = fmax(c2-c0, 0.0) * fmax(c3-c1, 0.0);
      const double iou = inter / (a1 + a2 - inter + 1e-8);
      if (iou > 0.7) bits |= (1ull << bcol);
    }
  }
  rowbits[(size_t)r*128 + g*16 + w] = bits;
}

// ---------------- greedy scan with suppression bitmap ----------------
__global__ __launch_bounds__(64) void greedy(
    const unsigned long long* __restrict__ skeys, const double* __restrict__ sboxd,
    const unsigned long long* __restrict__ rowbits, float* __restrict__ outp)
{
  const int t = threadIdx.x;
  const unsigned long long KEYTH = dkey(-5.0e8);   // valid iff score > NEG*0.5
  // first invalid rank (keys sorted desc)
  int bad = PRE_NMS;
  for (int j = t; j < PRE_NMS; j += 64){
    if (skeys[j] <= KEYTH){ bad = j; break; }
  }
  #pragma unroll
  for (int off = 32; off > 0; off >>= 1){
    const int o = __shfl_down(bad, off, 64);
    bad = (o < bad) ? o : bad;
  }
  const int ilim = __builtin_amdgcn_readfirstlane(bad);

  unsigned long long s0 = 0ull, s1 = 0ull;   // lane t owns words t and 64+t
  int emitted = 0;
  for (int i = 0; i < ilim && emitted < POST_NMS; ++i){
    const int w = i >> 6, b = i & 63;
    const unsigned long long w0 = shfl_u64(s0, w & 63);
    const unsigned long long w1 = shfl_u64(s1, (w - 64) & 63);
    const unsigned long long word = (w < 64) ? w0 : w1;
    if (!((word >> b) & 1ull)){
      if (t < 4) outp[4*emitted + t] = (float)sboxd[(size_t)i*4 + t];
      s0 |= rowbits[(size_t)i*128 + t];
      if (t < 30) s1 |= rowbits[(size_t)i*128 + 64 + t];
      ++emitted;
    }
  }
  for (int r = emitted; r < POST_NMS; ++r)
    if (t < 4) outp[4*r + t] = 0.f;
}

extern "C" void kernel_launch(void* const* d_in, const int* in_sizes, int n_in,
                              void* d_out, int out_size, void* d_ws, size_t ws_size,
                              hipStream_t stream)
{
  const float* fm   = (const float*)d_in[1];
  const float* amap = (const float*)d_in[2];
  const float* W1   = (const float*)d_in[4];
  const float* b1   = (const float*)d_in[5];
  const float* Wc   = (const float*)d_in[6];
  const float* bc   = (const float*)d_in[7];
  const float* Wr   = (const float*)d_in[8];
  const float* br   = (const float*)d_in[9];
  float* out = (float*)d_out;

  char* base = (char*)d_ws;
  size_t off = 0;
  auto A = [&](size_t n) -> char* {
    char* p = base + off;
    off = (off + n + 255) & ~(size_t)255;
    return p;
  };
  double* yd      = (double*)A(65536000);
  float*  WT2     = (float*) A(9437184);
  double* WcT     = (double*)A(36864);
  double* WrT     = (double*)A(147456);
  double* scored  = (double*)A(1152000);
  double* regd    = (double*)A(4608000);
  unsigned* histc = (unsigned*)A(524328);        // hist1|hist2|cnt|meta contiguous
  const size_t ovl = off;                         // overlay region (post-conv) aliases fmd
  double* fmd     = (double*)(base + ovl);        // 65,536,000 B when used
  double* boxesd              = (double*)A(4608000);
  unsigned long long* nmskey  = (unsigned long long*)A(1152000);
  unsigned* key32             = (unsigned*)A(576000);
  double* selboxd             = (double*)A(192000);
  unsigned long long* selkey  = (unsigned long long*)A(48000);
  unsigned long long* skeys   = (unsigned long long*)A(48000);
  double* sboxd               = (double*)A(192000);
  unsigned long long* rowbits = (unsigned long long*)A(6144000);
  int* eqidx                  = (int*)A(32768);

  unsigned* hist1 = histc;
  unsigned* hist2 = histc + 65536;
  int* cnt        = (int*)(histc + 131072);
  int* meta       = cnt + 2;

  const bool f64fm = (ovl + 65536000 <= ws_size);

  hipMemsetAsync(histc, 0, (size_t)524328, stream);

  hipLaunchKernelGGL(wtprep, dim3((9*512*512 + 255)/256), dim3(256), 0, stream, W1, WT2);
  hipLaunchKernelGGL(hwprep, dim3((45*512 + 255)/256), dim3(256), 0, stream, Wc, Wr, WcT, WrT);
  if (f64fm){
    hipLaunchKernelGGL(fmprep, dim3((NPIX*128 + 255)/256), dim3(256), 0, stream, fm, fmd);
    hipLaunchKernelGGL(conv3t<true>, dim3(2000), dim3(256), 0, stream, fm, fmd, WT2, b1, yd);
  } else {
    hipLaunchKernelGGL(conv3t<false>, dim3(2000), dim3(256), 0, stream, fm, fmd, WT2, b1, yd);
  }
  hipLaunchKernelGGL(head2, dim3(1000), dim3(256), 0, stream, yd, WcT, bc, WrT, br, out, scored, regd);
  hipLaunchKernelGGL(decode_kernel, dim3((NANCH + 255)/256), dim3(256), 0, stream,
                     amap, scored, regd, boxesd, key32, nmskey);
  hipLaunchKernelGGL(hist_hi, dim3((NANCH + 255)/256), dim3(256), 0, stream, key32, hist1);
  hipLaunchKernelGGL(scan_hi, dim3(1), dim3(1024), 0, stream, hist1, meta);
  hipLaunchKernelGGL(hist_lo, dim3((NANCH + 255)/256), dim3(256), 0, stream, key32, meta, hist2);
  hipLaunchKernelGGL(scan_lo, dim3(1), dim3(1024), 0, stream, hist2, meta);
  hipLaunchKernelGGL(compact_k, dim3((NANCH + 255)/256), dim3(256), 0, stream,
                     key32, nmskey, boxesd, meta, cnt, selboxd, selkey, eqidx);
  hipLaunchKernelGGL(rankeq, dim3(1), dim3(256), 0, stream,
                     scored, boxesd, nmskey, meta, cnt, eqidx, selboxd, selkey);
  hipLaunchKernelGGL(rank_scatter, dim3((PRE_NMS + 255)/256), dim3(256), 0, stream,
                     selkey, selboxd, skeys, sboxd);
  hipLaunchKernelGGL(iou_bitmap, dim3(375, 6), dim3(256), 0, stream, sboxd, rowbits);
  hipLaunchKernelGGL(greedy, dim3(1), dim3(64), 0, stream, skeys, sboxd, rowbits, out + 720000);
}